// Round 11
// baseline (143.518 us; speedup 1.0000x reference)
//
#include <hip/hip_runtime.h>
#include <hip/hip_bf16.h>
#include <math.h>

typedef unsigned short u16;
typedef unsigned int u32;
typedef __attribute__((ext_vector_type(8))) short short8;
typedef __attribute__((ext_vector_type(8))) unsigned short ushort8;
typedef __attribute__((ext_vector_type(4))) float floatx4;
typedef __attribute__((ext_vector_type(16))) float floatx16;
typedef __attribute__((ext_vector_type(4))) u32 uint4v;
typedef __attribute__((ext_vector_type(2))) float float2v;
typedef __attribute__((ext_vector_type(2))) int int2v;

#define CDIM   1024
#define TSEQ   2048
#define NHEAD  16
#define HDIM   64

// -1/(80*ln2): exp(-dist/80) = exp2(dist * C2)
#define C2_CONST  (-0.01803368801111874f)
#define M2C2_CONST (0.03606737602223748f)

static __device__ __forceinline__ u16 f2bf(float f) {
    u32 u = __float_as_uint(f);
    u += 0x7fffu + ((u >> 16) & 1u);   // RNE
    return (u16)(u >> 16);
}
static __device__ __forceinline__ float bf2f(u16 h) {
    return __uint_as_float(((u32)h) << 16);
}

// packed f32x2 -> bf16x2 (RNE), single VOP3
static __device__ __forceinline__ u32 cvtpk(float a, float b) {
    u32 r;
    asm("v_cvt_pk_bf16_f32 %0, %1, %2" : "=v"(r) : "v"(a), "v"(b));
    return r;
}

// fast tanh: 1 - 2/(exp2(2x*log2e)+1)
static __device__ __forceinline__ float ftanh(float x) {
    float e = exp2f(x * 2.88539008f);
    float r = __builtin_amdgcn_rcpf(e + 1.0f);
    return fmaf(-2.0f, r, 1.0f);
}

// async global->LDS, 16 bytes per lane
static __device__ __forceinline__ void gll16(const void* g, void* l) {
    __builtin_amdgcn_global_load_lds(
        (const __attribute__((address_space(1))) unsigned int*)g,
        (__attribute__((address_space(3))) unsigned int*)l, 16, 0, 0);
}

// ---------------------------------------------------------------------------
// prep: bid<4096 -> xa=tanh(x)+xsq ; else W mats (tanh+wsq for q/k/v, copy Wo)
__global__ __launch_bounds__(256) void prep(const float* __restrict__ x,
                                            const float* __restrict__ Wq, const float* __restrict__ Wk,
                                            const float* __restrict__ Wv, const float* __restrict__ Wo,
                                            u16* __restrict__ xa,
                                            u16* __restrict__ waq, u16* __restrict__ wak,
                                            u16* __restrict__ wav, u16* __restrict__ wob,
                                            float* __restrict__ xsq,
                                            float* __restrict__ sqq, float* __restrict__ sqk,
                                            float* __restrict__ sqv) {
    __shared__ float red[4];
    int bid = blockIdx.x, tid = threadIdx.x;
    const float* src; u16* dst; float* sq; int row; bool do_tanh = true;
    if (bid < 4096) {
        row = bid; src = x; dst = xa; sq = xsq;
    } else {
        int mat = (bid - 4096) >> 10; row = (bid - 4096) & 1023;
        src = (mat == 0) ? Wq : (mat == 1) ? Wk : (mat == 2) ? Wv : Wo;
        dst = (mat == 0) ? waq : (mat == 1) ? wak : (mat == 2) ? wav : wob;
        sq  = (mat == 0) ? sqq : (mat == 1) ? sqk : (mat == 2) ? sqv : nullptr;
        do_tanh = (mat < 3);
    }
    float4 v = reinterpret_cast<const float4*>(src + (size_t)row * CDIM)[tid];
    if (do_tanh) {
        float a0 = ftanh(v.x), a1 = ftanh(v.y), a2 = ftanh(v.z), a3 = ftanh(v.w);
        *reinterpret_cast<ushort4*>(dst + (size_t)row * CDIM + tid * 4) =
            make_ushort4(f2bf(a0), f2bf(a1), f2bf(a2), f2bf(a3));
        float s = a0*a0 + a1*a1 + a2*a2 + a3*a3;
        #pragma unroll
        for (int m = 1; m < 64; m <<= 1) s += __shfl_xor(s, m, 64);
        if ((tid & 63) == 0) red[tid >> 6] = s;
        __syncthreads();
        if (tid == 0 && sq) sq[row] = red[0] + red[1] + red[2] + red[3];
    } else {
        *reinterpret_cast<ushort4*>(dst + (size_t)row * CDIM + tid * 4) =
            make_ushort4(f2bf(v.x), f2bf(v.y), f2bf(v.z), f2bf(v.w));
    }
}

// ---------------------------------------------------------------------------
// Fused QKV GEMM: C = A * Bm^T, distance epilogue; z = 0(q)/1(k)/2(v).
// Outputs in MFMA-FRAGMENT layout for attn's direct global->reg loads:
//   q/k frag: [hb][tile32][kstep0..3][lane(hi*32+l31)][j]
//   v frag:   [hb][dt0..1][tile32][e0..1][lane(hi8*32+d31)][j]
__global__ __launch_bounds__(256) void gemm_qkv(const u16* __restrict__ xa,
                                                const u16* __restrict__ waq, const u16* __restrict__ wak, const u16* __restrict__ wav,
                                                u16* __restrict__ qF, u16* __restrict__ kF, u16* __restrict__ vF,
                                                const float* __restrict__ xsq,
                                                const float* __restrict__ sqq, const float* __restrict__ sqk, const float* __restrict__ sqv,
                                                const float* __restrict__ gq, const float* __restrict__ gk, const float* __restrict__ gv) {
    __shared__ __align__(16) u16 As[128 * 64];
    __shared__ __align__(16) u16 Bs[128 * 64];
    int z = blockIdx.z;
    const u16* Bm     = (z == 0) ? waq : (z == 1) ? wak : wav;
    const float* wsq  = (z == 0) ? sqq : (z == 1) ? sqk : sqv;
    const float* gain = (z == 0) ? gq : (z == 1) ? gk : gv;

    int tid = threadIdx.x;
    int m0 = blockIdx.y * 128, n0 = blockIdx.x * 128;
    int w = tid >> 6, l = tid & 63, wm = w >> 1, wn = w & 1, g = l >> 4, c = l & 15;
    int r8 = l >> 3, sl7 = l & 7;
    int cmask = (c & 7) ^ (c >> 3);

    floatx4 acc[4][4] = {};

    for (int kt = 0; kt < 16; ++kt) {
        __syncthreads();
        #pragma unroll
        for (int i = 0; i < 4; i++) {
            int ch = w * 4 + i;
            int row = ch * 8 + r8;
            int sl = sl7 ^ r8 ^ (ch & 1);
            gll16(xa + (size_t)(m0 + row) * CDIM + kt * 64 + sl * 8, &As[ch * 512 + l * 8]);
            gll16(Bm + (size_t)(n0 + row) * CDIM + kt * 64 + sl * 8, &Bs[ch * 512 + l * 8]);
        }
        __syncthreads();
        short8 af[2][4], bf[2][4];
        #pragma unroll
        for (int kk = 0; kk < 2; kk++) {
            #pragma unroll
            for (int mi = 0; mi < 4; mi++)
                af[kk][mi] = *reinterpret_cast<const short8*>(
                    &As[(wm * 64 + mi * 16 + c) * 64 + (((kk * 4 + g) ^ cmask) << 3)]);
            #pragma unroll
            for (int ni = 0; ni < 4; ni++)
                bf[kk][ni] = *reinterpret_cast<const short8*>(
                    &Bs[(wn * 64 + ni * 16 + c) * 64 + (((kk * 4 + g) ^ cmask) << 3)]);
        }
        #pragma unroll
        for (int kk = 0; kk < 2; kk++)
            #pragma unroll
            for (int mi = 0; mi < 4; mi++)
                #pragma unroll
                for (int ni = 0; ni < 4; ni++)
                    acc[mi][ni] = __builtin_amdgcn_mfma_f32_16x16x32_bf16(af[kk][mi], bf[kk][ni], acc[mi][ni], 0, 0, 0);
    }

    if (z < 2) {
        u16* outF = (z == 0) ? qF : kF;
        #pragma unroll
        for (int mi = 0; mi < 4; mi++) {
            int rowb = m0 + wm * 64 + mi * 16 + g * 4;
            int bb = rowb >> 11, tt = rowb & 2047;
            int tile = tt >> 5, l31 = tt & 31;
            #pragma unroll
            for (int ni = 0; ni < 4; ni++) {
                int col = n0 + wn * 64 + ni * 16 + c;
                int hh = col >> 6, d = col & 63;
                int kst = d >> 4, hi8 = (d >> 3) & 1, j = d & 7;
                size_t base = ((((size_t)(bb * NHEAD + hh) * 64 + tile) * 4 + kst) * 2 + hi8) * 256 + j;
                float wsqc = wsq[col], gn = gain[col];
                #pragma unroll
                for (int r = 0; r < 4; r++) {
                    float l2 = fmaxf(xsq[rowb + r] + wsqc - 2.f * acc[mi][ni][r], 0.f);
                    float th = ftanh((0.5f - l2 * (1.f / 1024.f)) * gn);
                    outF[base + (size_t)(l31 + r) * 8] = f2bf(th);
                }
            }
        }
    } else {  // v: store in PV B-fragment layout
        #pragma unroll
        for (int mi = 0; mi < 4; mi++) {
            int rowb = m0 + wm * 64 + mi * 16 + g * 4;
            int bb = rowb >> 11, s = rowb & 2047;
            int tile = s >> 5, e = (s >> 4) & 1, hi8 = (s >> 3) & 1, j0 = s & 7;
            #pragma unroll
            for (int ni = 0; ni < 4; ni++) {
                int col = n0 + wn * 64 + ni * 16 + c;
                int hh = col >> 6, d = col & 63;
                int dt = d >> 5, l31 = d & 31;
                float wsqc = wsq[col], gn = gain[col];
                float vals[4];
                #pragma unroll
                for (int r = 0; r < 4; r++) {
                    float l2 = fmaxf(xsq[rowb + r] + wsqc - 2.f * acc[mi][ni][r], 0.f);
                    vals[r] = (0.5f - l2 * (1.f / 1024.f)) * gn;
                }
                size_t idx = (((((size_t)(bb * NHEAD + hh) * 2 + dt) * 64 + tile) * 2 + e) * 2 + hi8) * 256
                             + (size_t)l31 * 8 + j0;
                *reinterpret_cast<ushort4*>(&vF[idx]) =
                    make_ushort4(f2bf(vals[0]), f2bf(vals[1]), f2bf(vals[2]), f2bf(vals[3]));
            }
        }
    }
}

// ---------------------------------------------------------------------------
// knorm: ksC2T[hb*2048 + t] = C2 * sum_d k[t][d]^2, read from kF fragments.
__global__ __launch_bounds__(256) void knorm(const u16* __restrict__ kF,
                                             float* __restrict__ ksC2T) {
    int hb = blockIdx.x >> 3, seg = blockIdx.x & 7;
    int tile = seg * 8 + (threadIdx.x >> 5), t32 = threadIdx.x & 31;
    const u16* base = kF + ((size_t)hb * 64 + tile) * 2048 + t32 * 8;
    float s = 0.f;
    #pragma unroll
    for (int kst = 0; kst < 4; kst++)
        #pragma unroll
        for (int hi8 = 0; hi8 < 2; hi8++) {
            ushort8 v = *reinterpret_cast<const ushort8*>(base + (kst * 2 + hi8) * 256);
            #pragma unroll
            for (int j = 0; j < 8; j++) { float f = bf2f(v[j]); s += f * f; }
        }
    ksC2T[(size_t)hb * TSEQ + tile * 32 + t32] = s * C2_CONST;
}

// ---------------------------------------------------------------------------
// Final GEMM: out = ao * Wo^T, f32 store.
__global__ __launch_bounds__(256) void gemm_out(const u16* __restrict__ A, const u16* __restrict__ Bm,
                                                float* __restrict__ outF) {
    __shared__ __align__(16) u16 As[128 * 64];
    __shared__ __align__(16) u16 Bs[128 * 64];
    int tid = threadIdx.x;
    int m0 = blockIdx.y * 128, n0 = blockIdx.x * 128;
    int w = tid >> 6, l = tid & 63, wm = w >> 1, wn = w & 1, g = l >> 4, c = l & 15;
    int r8 = l >> 3, sl7 = l & 7;
    int cmask = (c & 7) ^ (c >> 3);

    floatx4 acc[4][4] = {};

    for (int kt = 0; kt < 16; ++kt) {
        __syncthreads();
        #pragma unroll
        for (int i = 0; i < 4; i++) {
            int ch = w * 4 + i;
            int row = ch * 8 + r8;
            int sl = sl7 ^ r8 ^ (ch & 1);
            gll16(A + (size_t)(m0 + row) * CDIM + kt * 64 + sl * 8, &As[ch * 512 + l * 8]);
            gll16(Bm + (size_t)(n0 + row) * CDIM + kt * 64 + sl * 8, &Bs[ch * 512 + l * 8]);
        }
        __syncthreads();
        short8 af[2][4], bf[2][4];
        #pragma unroll
        for (int kk = 0; kk < 2; kk++) {
            #pragma unroll
            for (int mi = 0; mi < 4; mi++)
                af[kk][mi] = *reinterpret_cast<const short8*>(
                    &As[(wm * 64 + mi * 16 + c) * 64 + (((kk * 4 + g) ^ cmask) << 3)]);
            #pragma unroll
            for (int ni = 0; ni < 4; ni++)
                bf[kk][ni] = *reinterpret_cast<const short8*>(
                    &Bs[(wn * 64 + ni * 16 + c) * 64 + (((kk * 4 + g) ^ cmask) << 3)]);
        }
        #pragma unroll
        for (int kk = 0; kk < 2; kk++)
            #pragma unroll
            for (int mi = 0; mi < 4; mi++)
                #pragma unroll
                for (int ni = 0; ni < 4; ni++)
                    acc[mi][ni] = __builtin_amdgcn_mfma_f32_16x16x32_bf16(af[kk][mi], bf[kk][ni], acc[mi][ni], 0, 0, 0);
    }

    #pragma unroll
    for (int mi = 0; mi < 4; mi++) {
        int rowb = m0 + wm * 64 + mi * 16 + g * 4;
        #pragma unroll
        for (int ni = 0; ni < 4; ni++) {
            int col = n0 + wn * 64 + ni * 16 + c;
            #pragma unroll
            for (int r = 0; r < 4; r++)
                outF[(size_t)(rowb + r) * CDIM + col] = acc[mi][ni][r];
        }
    }
}

// ---------------------------------------------------------------------------
// attn11: 64 q-columns per wave (2 qf sets) -> K/V L2 traffic halved.
// LDS-free main loop; permlane exchange; fixed-m softmax; ksb loads shared
// between qsets. 4 s-chunks/block; grid 1024 (32 ttiles(64q) x 32 hb).
__global__ __launch_bounds__(256, 2) void attn11(const u16* __restrict__ qF, const u16* __restrict__ kF,
                                                 const u16* __restrict__ vF,
                                                 const float* __restrict__ ksC2T, u16* __restrict__ ao) {
    int bid = blockIdx.x;
    int hb = bid & 31;
    int ttile = bid >> 5;              // 0..31, 64 q-rows each
    int tid = threadIdx.x, sc = tid >> 6, l = tid & 63;
    int hi = l >> 5, t32 = l & 31;

    __shared__ float redO[2][64][33];
    __shared__ float Ls[32];

    const u16* qbase = qF + ((size_t)hb * 64 + ttile * 2) * 2048;
    short8 qfA[4], qfB[4];
    #pragma unroll
    for (int ks = 0; ks < 4; ks++) {
        qfA[ks] = *reinterpret_cast<const short8*>(qbase + ks * 512 + (size_t)l * 8);
        qfB[ks] = *reinterpret_cast<const short8*>(qbase + 2048 + ks * 512 + (size_t)l * 8);
    }

    const u16* kbase = kF + (size_t)hb * (64 * 2048);
    const u16* vbase = vF + (size_t)hb * (2 * 64 * 1024);
    const float* ksb = ksC2T + (size_t)hb * TSEQ;

    floatx16 oA[2] = {}, oB[2] = {};
    float lA = 0.f, lB = 0.f;

    int st0 = sc * 16;
    for (int st = st0; st < st0 + 16; ++st) {
        const short8* kp = reinterpret_cast<const short8*>(kbase + (size_t)st * 2048) + l;
        short8 kf0 = kp[0], kf1 = kp[64], kf2 = kp[128], kf3 = kp[192];
        const short8* vp = reinterpret_cast<const short8*>(vbase + (size_t)st * 1024) + l;
        short8 vf00 = vp[0], vf01 = vp[64];
        short8 vf10 = vp[8192], vf11 = vp[8256];

        float4 kc[4];
        #pragma unroll
        for (int qq = 0; qq < 4; qq++)
            kc[qq] = *reinterpret_cast<const float4*>(&ksb[st * 32 + qq * 8 + hi * 4]);

        // ---- qset A: S^T then softmax/pack
        __builtin_amdgcn_s_setprio(1);
        floatx16 sxx = {};
        sxx = __builtin_amdgcn_mfma_f32_32x32x16_bf16(kf0, qfA[0], sxx, 0, 0, 0);
        sxx = __builtin_amdgcn_mfma_f32_32x32x16_bf16(kf1, qfA[1], sxx, 0, 0, 0);
        sxx = __builtin_amdgcn_mfma_f32_32x32x16_bf16(kf2, qfA[2], sxx, 0, 0, 0);
        sxx = __builtin_amdgcn_mfma_f32_32x32x16_bf16(kf3, qfA[3], sxx, 0, 0, 0);
        __builtin_amdgcn_s_setprio(0);
        u32 pkA[8];
        #pragma unroll
        for (int qq = 0; qq < 4; qq++) {
            float p0 = exp2f(fmaf(sxx[qq * 4 + 0], M2C2_CONST, kc[qq].x));
            float p1 = exp2f(fmaf(sxx[qq * 4 + 1], M2C2_CONST, kc[qq].y));
            float p2 = exp2f(fmaf(sxx[qq * 4 + 2], M2C2_CONST, kc[qq].z));
            float p3 = exp2f(fmaf(sxx[qq * 4 + 3], M2C2_CONST, kc[qq].w));
            lA += (p0 + p1) + (p2 + p3);
            pkA[qq * 2]     = cvtpk(p0, p1);
            pkA[qq * 2 + 1] = cvtpk(p2, p3);
        }

        // ---- qset B: S^T then softmax/pack (reuses kf, kc)
        __builtin_amdgcn_s_setprio(1);
        floatx16 syy = {};
        syy = __builtin_amdgcn_mfma_f32_32x32x16_bf16(kf0, qfB[0], syy, 0, 0, 0);
        syy = __builtin_amdgcn_mfma_f32_32x32x16_bf16(kf1, qfB[1], syy, 0, 0, 0);
        syy = __builtin_amdgcn_mfma_f32_32x32x16_bf16(kf2, qfB[2], syy, 0, 0, 0);
        syy = __builtin_amdgcn_mfma_f32_32x32x16_bf16(kf3, qfB[3], syy, 0, 0, 0);
        __builtin_amdgcn_s_setprio(0);
        u32 pkB[8];
        #pragma unroll
        for (int qq = 0; qq < 4; qq++) {
            float p0 = exp2f(fmaf(syy[qq * 4 + 0], M2C2_CONST, kc[qq].x));
            float p1 = exp2f(fmaf(syy[qq * 4 + 1], M2C2_CONST, kc[qq].y));
            float p2 = exp2f(fmaf(syy[qq * 4 + 2], M2C2_CONST, kc[qq].z));
            float p3 = exp2f(fmaf(syy[qq * 4 + 3], M2C2_CONST, kc[qq].w));
            lB += (p0 + p1) + (p2 + p3);
            pkB[qq * 2]     = cvtpk(p0, p1);
            pkB[qq * 2 + 1] = cvtpk(p2, p3);
        }

        // ---- PV for both qsets (permlane exchange, V fragments reused)
        __builtin_amdgcn_s_setprio(1);
        #pragma unroll
        for (int e = 0; e < 2; e++) {
            int2v a02 = __builtin_amdgcn_permlane32_swap((int)pkA[4 * e + 2], (int)pkA[4 * e + 0], false, false);
            int2v a13 = __builtin_amdgcn_permlane32_swap((int)pkA[4 * e + 3], (int)pkA[4 * e + 1], false, false);
            uint4v auA; auA.x = (u32)a02.y; auA.y = (u32)a13.y; auA.z = (u32)a02.x; auA.w = (u32)a13.x;
            short8 afA = __builtin_bit_cast(short8, auA);
            oA[0] = __builtin_amdgcn_mfma_f32_32x32x16_bf16(afA, e ? vf01 : vf00, oA[0], 0, 0, 0);
            oA[1] = __builtin_amdgcn_mfma_f32_32x32x16_bf16(afA, e ? vf11 : vf10, oA[1], 0, 0, 0);

            int2v b02 = __builtin_amdgcn_permlane32_swap((int)pkB[4 * e + 2], (int)pkB[4 * e + 0], false, false);
            int2v b13 = __builtin_amdgcn_permlane32_swap((int)pkB[4 * e + 3], (int)pkB[4 * e + 1], false, false);
            uint4v auB; auB.x = (u32)b02.y; auB.y = (u32)b13.y; auB.z = (u32)b02.x; auB.w = (u32)b13.x;
            short8 afB = __builtin_bit_cast(short8, auB);
            oB[0] = __builtin_amdgcn_mfma_f32_32x32x16_bf16(afB, e ? vf01 : vf00, oB[0], 0, 0, 0);
            oB[1] = __builtin_amdgcn_mfma_f32_32x32x16_bf16(afB, e ? vf11 : vf10, oB[1], 0, 0, 0);
        }
        __builtin_amdgcn_s_setprio(0);
    }

    int b = hb >> 4, h = hb & 15;
    // ---- combine + write, qset A then qset B (reusing redO)
    #pragma unroll
    for (int qs = 0; qs < 2; qs++) {
        floatx16* oacc = qs ? oB : oA;
        float lrun = qs ? lB : lA;
        if (qs) __syncthreads();        // protect redO reuse from pass A
        if (sc == 1 || sc == 3) {
            int sid = sc >> 1;
            #pragma unroll
            for (int dt = 0; dt < 2; dt++)
                #pragma unroll
                for (int r = 0; r < 16; r++)
                    redO[sid][l][dt * 16 + r] = oacc[dt][r];
            redO[sid][l][32] = lrun;
        }
        __syncthreads();
        if (sc == 0 || sc == 2) {
            int sid = sc >> 1;
            #pragma unroll
            for (int dt = 0; dt < 2; dt++)
                #pragma unroll
                for (int r = 0; r < 16; r++)
                    oacc[dt][r] += redO[sid][l][dt * 16 + r];
            lrun += redO[sid][l][32];
        }
        __syncthreads();
        if (sc == 2) {
            #pragma unroll
            for (int dt = 0; dt < 2; dt++)
                #pragma unroll
                for (int r = 0; r < 16; r++)
                    redO[0][l][dt * 16 + r] = oacc[dt][r];
            redO[0][l][32] = lrun;
        }
        __syncthreads();
        if (sc == 0) {
            #pragma unroll
            for (int dt = 0; dt < 2; dt++)
                #pragma unroll
                for (int r = 0; r < 16; r++)
                    oacc[dt][r] += redO[0][l][dt * 16 + r];
            lrun += redO[0][l][32];

            float ltot = lrun + __shfl_xor(lrun, 32, 64);
            if (l < 32) Ls[l] = ltot;
            int twb = ttile * 64 + qs * 32;
            float4 lv[4];
            #pragma unroll
            for (int qq = 0; qq < 4; qq++)
                lv[qq] = *reinterpret_cast<const float4*>(&Ls[qq * 8 + hi * 4]);
            #pragma unroll
            for (int dt = 0; dt < 2; dt++)
                #pragma unroll
                for (int r = 0; r < 16; ++r) {
                    int trow = (r & 3) + 8 * (r >> 2) + 4 * hi;
                    float lval = (r & 3) == 0 ? lv[r >> 2].x : (r & 3) == 1 ? lv[r >> 2].y
                               : (r & 3) == 2 ? lv[r >> 2].z : lv[r >> 2].w;
                    ao[(size_t)(b * TSEQ + twb + trow) * CDIM + h * HDIM + dt * 32 + t32] =
                        f2bf(oacc[dt][r] * __builtin_amdgcn_rcpf(lval));
                }
        }
    }
}

// ---------------------------------------------------------------------------
extern "C" void kernel_launch(void* const* d_in, const int* in_sizes, int n_in,
                              void* d_out, int out_size, void* d_ws, size_t ws_size,
                              hipStream_t stream) {
    const float* x  = (const float*)d_in[0];
    const float* Wq = (const float*)d_in[1];
    const float* gq = (const float*)d_in[2];
    const float* Wk = (const float*)d_in[3];
    const float* gk = (const float*)d_in[4];
    const float* Wv = (const float*)d_in[5];
    const float* gv = (const float*)d_in[6];
    const float* Wo = (const float*)d_in[7];
    float* out = (float*)d_out;

    char* p = (char*)d_ws;
    u16* xa  = (u16*)p;  p += (size_t)8 << 20;
    u16* qF  = (u16*)p;  p += (size_t)8 << 20;
    u16* kF  = (u16*)p;  p += (size_t)8 << 20;
    u16* vF  = (u16*)p;  p += (size_t)8 << 20;
    u16* ao  = (u16*)p;  p += (size_t)8 << 20;
    u16* waq = (u16*)p;  p += (size_t)2 << 20;
    u16* wak = (u16*)p;  p += (size_t)2 << 20;
    u16* wav = (u16*)p;  p += (size_t)2 << 20;
    u16* wob = (u16*)p;  p += (size_t)2 << 20;
    float* xsq   = (float*)p; p += 4096 * 4;
    float* sqq   = (float*)p; p += 1024 * 4;
    float* sqk   = (float*)p; p += 1024 * 4;
    float* sqv   = (float*)p; p += 1024 * 4;
    float* ksC2T = (float*)p; p += 4096 * 16 * 4;
    (void)ws_size; (void)in_sizes; (void)n_in; (void)out_size;

    prep<<<8192, 256, 0, stream>>>(x, Wq, Wk, Wv, Wo, xa, waq, wak, wav, wob,
                                   xsq, sqq, sqk, sqv);

    dim3 gqkv(8, 32, 3);
    gemm_qkv<<<gqkv, 256, 0, stream>>>(xa, waq, wak, wav, qF, kF, vF, xsq,
                                       sqq, sqk, sqv, gq, gk, gv);

    knorm<<<256, 256, 0, stream>>>(kF, ksC2T);

    attn11<<<1024, 256, 0, stream>>>(qF, kF, vF, ksC2T, ao);

    dim3 gg(8, 32);
    gemm_out<<<gg, 256, 0, stream>>>(ao, wob, out);
}

// Round 12
// 143.226 us; speedup vs baseline: 1.0020x; 1.0020x over previous
//
#include <hip/hip_runtime.h>
#include <hip/hip_bf16.h>
#include <math.h>

typedef unsigned short u16;
typedef unsigned int u32;
typedef __attribute__((ext_vector_type(8))) short short8;
typedef __attribute__((ext_vector_type(8))) unsigned short ushort8;
typedef __attribute__((ext_vector_type(4))) float floatx4;
typedef __attribute__((ext_vector_type(16))) float floatx16;
typedef __attribute__((ext_vector_type(4))) u32 uint4v;
typedef __attribute__((ext_vector_type(2))) int int2v;

#define CDIM   1024
#define TSEQ   2048
#define NHEAD  16
#define HDIM   64

// -1/(80*ln2): exp(-dist/80) = exp2(dist * C2)
#define C2_CONST  (-0.01803368801111874f)
#define M2C2_CONST (0.03606737602223748f)

static __device__ __forceinline__ u16 f2bf(float f) {
    u32 u = __float_as_uint(f);
    u += 0x7fffu + ((u >> 16) & 1u);   // RNE
    return (u16)(u >> 16);
}
static __device__ __forceinline__ float bf2f(u16 h) {
    return __uint_as_float(((u32)h) << 16);
}

// packed f32x2 -> bf16x2 (RNE), single VOP3
static __device__ __forceinline__ u32 cvtpk(float a, float b) {
    u32 r;
    asm("v_cvt_pk_bf16_f32 %0, %1, %2" : "=v"(r) : "v"(a), "v"(b));
    return r;
}

// fast tanh: 1 - 2/(exp2(2x*log2e)+1)
static __device__ __forceinline__ float ftanh(float x) {
    float e = exp2f(x * 2.88539008f);
    float r = __builtin_amdgcn_rcpf(e + 1.0f);
    return fmaf(-2.0f, r, 1.0f);
}

// async global->LDS, 16 bytes per lane
static __device__ __forceinline__ void gll16(const void* g, void* l) {
    __builtin_amdgcn_global_load_lds(
        (const __attribute__((address_space(1))) unsigned int*)g,
        (__attribute__((address_space(3))) unsigned int*)l, 16, 0, 0);
}

// ---------------------------------------------------------------------------
// prep: bid<4096 -> xa=tanh(x)+xsq ; else W mats (tanh+wsq for q/k/v, copy Wo)
__global__ __launch_bounds__(256) void prep(const float* __restrict__ x,
                                            const float* __restrict__ Wq, const float* __restrict__ Wk,
                                            const float* __restrict__ Wv, const float* __restrict__ Wo,
                                            u16* __restrict__ xa,
                                            u16* __restrict__ waq, u16* __restrict__ wak,
                                            u16* __restrict__ wav, u16* __restrict__ wob,
                                            float* __restrict__ xsq,
                                            float* __restrict__ sqq, float* __restrict__ sqk,
                                            float* __restrict__ sqv) {
    __shared__ float red[4];
    int bid = blockIdx.x, tid = threadIdx.x;
    const float* src; u16* dst; float* sq; int row; bool do_tanh = true;
    if (bid < 4096) {
        row = bid; src = x; dst = xa; sq = xsq;
    } else {
        int mat = (bid - 4096) >> 10; row = (bid - 4096) & 1023;
        src = (mat == 0) ? Wq : (mat == 1) ? Wk : (mat == 2) ? Wv : Wo;
        dst = (mat == 0) ? waq : (mat == 1) ? wak : (mat == 2) ? wav : wob;
        sq  = (mat == 0) ? sqq : (mat == 1) ? sqk : (mat == 2) ? sqv : nullptr;
        do_tanh = (mat < 3);
    }
    float4 v = reinterpret_cast<const float4*>(src + (size_t)row * CDIM)[tid];
    if (do_tanh) {
        float a0 = ftanh(v.x), a1 = ftanh(v.y), a2 = ftanh(v.z), a3 = ftanh(v.w);
        *reinterpret_cast<ushort4*>(dst + (size_t)row * CDIM + tid * 4) =
            make_ushort4(f2bf(a0), f2bf(a1), f2bf(a2), f2bf(a3));
        float s = a0*a0 + a1*a1 + a2*a2 + a3*a3;
        #pragma unroll
        for (int m = 1; m < 64; m <<= 1) s += __shfl_xor(s, m, 64);
        if ((tid & 63) == 0) red[tid >> 6] = s;
        __syncthreads();
        if (tid == 0 && sq) sq[row] = red[0] + red[1] + red[2] + red[3];
    } else {
        *reinterpret_cast<ushort4*>(dst + (size_t)row * CDIM + tid * 4) =
            make_ushort4(f2bf(v.x), f2bf(v.y), f2bf(v.z), f2bf(v.w));
    }
}

// ---------------------------------------------------------------------------
// Fused QKV GEMM: C = A * Bm^T, distance epilogue; z = 0(q)/1(k)/2(v).
// Outputs in MFMA-FRAGMENT layout, written via LDS-bounce + linear copy-out
// (per-block destination regions are contiguous in the fragment layout):
//   q/k frag: [hb][tile32][kstep0..3][hi8][l31*8+j]  (2048 u16 per tile)
//   v frag:   [hb][dt0..1][tile32][e0..1][hi8][l31*8+j0]  (1024 u16 per tile)
__global__ __launch_bounds__(256) void gemm_qkv(const u16* __restrict__ xa,
                                                const u16* __restrict__ waq, const u16* __restrict__ wak, const u16* __restrict__ wav,
                                                u16* __restrict__ qF, u16* __restrict__ kF, u16* __restrict__ vF,
                                                const float* __restrict__ xsq,
                                                const float* __restrict__ sqq, const float* __restrict__ sqk, const float* __restrict__ sqv,
                                                const float* __restrict__ gq, const float* __restrict__ gk, const float* __restrict__ gv) {
    __shared__ __align__(16) u16 SMEM[2 * 128 * 64];   // As|Bs in loop; 32KB frag-staging in epilogue
    u16* As = SMEM;
    u16* Bs = SMEM + 128 * 64;
    int z = blockIdx.z;
    const u16* Bm     = (z == 0) ? waq : (z == 1) ? wak : wav;
    const float* wsq  = (z == 0) ? sqq : (z == 1) ? sqk : sqv;
    const float* gain = (z == 0) ? gq : (z == 1) ? gk : gv;

    int tid = threadIdx.x;
    int m0 = blockIdx.y * 128, n0 = blockIdx.x * 128;
    int w = tid >> 6, l = tid & 63, wm = w >> 1, wn = w & 1, g = l >> 4, c = l & 15;
    int r8 = l >> 3, sl7 = l & 7;
    int cmask = (c & 7) ^ (c >> 3);

    floatx4 acc[4][4] = {};

    for (int kt = 0; kt < 16; ++kt) {
        __syncthreads();
        #pragma unroll
        for (int i = 0; i < 4; i++) {
            int ch = w * 4 + i;
            int row = ch * 8 + r8;
            int sl = sl7 ^ r8 ^ (ch & 1);
            gll16(xa + (size_t)(m0 + row) * CDIM + kt * 64 + sl * 8, &As[ch * 512 + l * 8]);
            gll16(Bm + (size_t)(n0 + row) * CDIM + kt * 64 + sl * 8, &Bs[ch * 512 + l * 8]);
        }
        __syncthreads();
        short8 af[2][4], bf[2][4];
        #pragma unroll
        for (int kk = 0; kk < 2; kk++) {
            #pragma unroll
            for (int mi = 0; mi < 4; mi++)
                af[kk][mi] = *reinterpret_cast<const short8*>(
                    &As[(wm * 64 + mi * 16 + c) * 64 + (((kk * 4 + g) ^ cmask) << 3)]);
            #pragma unroll
            for (int ni = 0; ni < 4; ni++)
                bf[kk][ni] = *reinterpret_cast<const short8*>(
                    &Bs[(wn * 64 + ni * 16 + c) * 64 + (((kk * 4 + g) ^ cmask) << 3)]);
        }
        #pragma unroll
        for (int kk = 0; kk < 2; kk++)
            #pragma unroll
            for (int mi = 0; mi < 4; mi++)
                #pragma unroll
                for (int ni = 0; ni < 4; ni++)
                    acc[mi][ni] = __builtin_amdgcn_mfma_f32_16x16x32_bf16(af[kk][mi], bf[kk][ni], acc[mi][ni], 0, 0, 0);
    }

    __syncthreads();   // all MFMA LDS reads complete before SMEM reuse

    int bb = m0 >> 11;                 // batch
    int tile0 = (m0 & 2047) >> 5;      // first 32-row tile (multiple of 4)
    int hh0 = blockIdx.x * 2;          // first head of this block's 128 cols

    if (z < 2) {
        u16* outF = (z == 0) ? qF : kF;
        // ---- scatter into SMEM in attn-frag layout:
        // lidx = hh2*8192 + tile4*2048 + kst*512 + hi8*256 + l31*8 + j
        #pragma unroll
        for (int mi = 0; mi < 4; mi++) {
            int rowb = m0 + wm * 64 + mi * 16 + g * 4;
            int tile4 = (rowb & 127) >> 5;
            int l31 = rowb & 31;       // rowb%32; +r below (r<4, l31%4==0)
            #pragma unroll
            for (int ni = 0; ni < 4; ni++) {
                int col = n0 + wn * 64 + ni * 16 + c;
                int hh2 = (col >> 6) & 1;
                int d = col & 63;
                int kst = d >> 4, hi8 = (d >> 3) & 1, j = d & 7;
                int lidx = hh2 * 8192 + tile4 * 2048 + kst * 512 + hi8 * 256 + l31 * 8 + j;
                float wsqc = wsq[col], gn = gain[col];
                #pragma unroll
                for (int r = 0; r < 4; r++) {
                    float l2 = fmaxf(xsq[rowb + r] + wsqc - 2.f * acc[mi][ni][r], 0.f);
                    float th = ftanh((0.5f - l2 * (1.f / 1024.f)) * gn);
                    SMEM[lidx + r * 8] = f2bf(th);
                }
            }
        }
        __syncthreads();
        // ---- linear copy-out: 2 contiguous spans of 8192 u16 (one per head)
        #pragma unroll
        for (int hh2 = 0; hh2 < 2; hh2++) {
            u16* gdst = outF + (((size_t)(bb * NHEAD + hh0 + hh2) * 64 + tile0) * 2048);
            #pragma unroll
            for (int i = 0; i < 4; i++) {
                int off = i * 2048 + tid * 8;
                *reinterpret_cast<ushort8*>(gdst + off) =
                    *reinterpret_cast<const ushort8*>(&SMEM[hh2 * 8192 + off]);
            }
        }
    } else {
        // ---- v: scatter into SMEM in PV B-frag layout:
        // lidx = hh2*8192 + dt*4096 + tile4*1024 + e*512 + hi8*256 + l31*8 + j0
        #pragma unroll
        for (int mi = 0; mi < 4; mi++) {
            int rowb = m0 + wm * 64 + mi * 16 + g * 4;   // s
            int tile4 = (rowb & 127) >> 5;
            int e = (rowb >> 4) & 1, hi8 = (rowb >> 3) & 1, j0 = rowb & 7;
            #pragma unroll
            for (int ni = 0; ni < 4; ni++) {
                int col = n0 + wn * 64 + ni * 16 + c;
                int hh2 = (col >> 6) & 1;
                int d = col & 63;
                int dt = d >> 5, l31 = d & 31;
                float wsqc = wsq[col], gn = gain[col];
                float vals[4];
                #pragma unroll
                for (int r = 0; r < 4; r++) {
                    float l2 = fmaxf(xsq[rowb + r] + wsqc - 2.f * acc[mi][ni][r], 0.f);
                    vals[r] = (0.5f - l2 * (1.f / 1024.f)) * gn;
                }
                int lidx = hh2 * 8192 + dt * 4096 + tile4 * 1024 + e * 512 + hi8 * 256 + l31 * 8 + j0;
                *reinterpret_cast<ushort4*>(&SMEM[lidx]) =
                    make_ushort4(f2bf(vals[0]), f2bf(vals[1]), f2bf(vals[2]), f2bf(vals[3]));
            }
        }
        __syncthreads();
        // ---- linear copy-out: 4 contiguous spans of 4096 u16 per (head, dt)
        #pragma unroll
        for (int hh2 = 0; hh2 < 2; hh2++)
            #pragma unroll
            for (int dt = 0; dt < 2; dt++) {
                u16* gdst = vF + ((((size_t)(bb * NHEAD + hh0 + hh2) * 2 + dt) * 64 + tile0) * 1024);
                #pragma unroll
                for (int i = 0; i < 2; i++) {
                    int off = i * 2048 + tid * 8;
                    *reinterpret_cast<ushort8*>(gdst + off) =
                        *reinterpret_cast<const ushort8*>(&SMEM[hh2 * 8192 + dt * 4096 + off]);
                }
            }
    }
}

// ---------------------------------------------------------------------------
// knorm: ksC2T[hb*2048 + t] = C2 * sum_d k[t][d]^2, read from kF fragments.
__global__ __launch_bounds__(256) void knorm(const u16* __restrict__ kF,
                                             float* __restrict__ ksC2T) {
    int hb = blockIdx.x >> 3, seg = blockIdx.x & 7;
    int tile = seg * 8 + (threadIdx.x >> 5), t32 = threadIdx.x & 31;
    const u16* base = kF + ((size_t)hb * 64 + tile) * 2048 + t32 * 8;
    float s = 0.f;
    #pragma unroll
    for (int kst = 0; kst < 4; kst++)
        #pragma unroll
        for (int hi8 = 0; hi8 < 2; hi8++) {
            ushort8 v = *reinterpret_cast<const ushort8*>(base + (kst * 2 + hi8) * 256);
            #pragma unroll
            for (int j = 0; j < 8; j++) { float f = bf2f(v[j]); s += f * f; }
        }
    ksC2T[(size_t)hb * TSEQ + tile * 32 + t32] = s * C2_CONST;
}

// ---------------------------------------------------------------------------
// Final GEMM: out = ao * Wo^T, f32 store.
__global__ __launch_bounds__(256) void gemm_out(const u16* __restrict__ A, const u16* __restrict__ Bm,
                                                float* __restrict__ outF) {
    __shared__ __align__(16) u16 As[128 * 64];
    __shared__ __align__(16) u16 Bs[128 * 64];
    int tid = threadIdx.x;
    int m0 = blockIdx.y * 128, n0 = blockIdx.x * 128;
    int w = tid >> 6, l = tid & 63, wm = w >> 1, wn = w & 1, g = l >> 4, c = l & 15;
    int r8 = l >> 3, sl7 = l & 7;
    int cmask = (c & 7) ^ (c >> 3);

    floatx4 acc[4][4] = {};

    for (int kt = 0; kt < 16; ++kt) {
        __syncthreads();
        #pragma unroll
        for (int i = 0; i < 4; i++) {
            int ch = w * 4 + i;
            int row = ch * 8 + r8;
            int sl = sl7 ^ r8 ^ (ch & 1);
            gll16(A + (size_t)(m0 + row) * CDIM + kt * 64 + sl * 8, &As[ch * 512 + l * 8]);
            gll16(Bm + (size_t)(n0 + row) * CDIM + kt * 64 + sl * 8, &Bs[ch * 512 + l * 8]);
        }
        __syncthreads();
        short8 af[2][4], bf[2][4];
        #pragma unroll
        for (int kk = 0; kk < 2; kk++) {
            #pragma unroll
            for (int mi = 0; mi < 4; mi++)
                af[kk][mi] = *reinterpret_cast<const short8*>(
                    &As[(wm * 64 + mi * 16 + c) * 64 + (((kk * 4 + g) ^ cmask) << 3)]);
            #pragma unroll
            for (int ni = 0; ni < 4; ni++)
                bf[kk][ni] = *reinterpret_cast<const short8*>(
                    &Bs[(wn * 64 + ni * 16 + c) * 64 + (((kk * 4 + g) ^ cmask) << 3)]);
        }
        #pragma unroll
        for (int kk = 0; kk < 2; kk++)
            #pragma unroll
            for (int mi = 0; mi < 4; mi++)
                #pragma unroll
                for (int ni = 0; ni < 4; ni++)
                    acc[mi][ni] = __builtin_amdgcn_mfma_f32_16x16x32_bf16(af[kk][mi], bf[kk][ni], acc[mi][ni], 0, 0, 0);
    }

    #pragma unroll
    for (int mi = 0; mi < 4; mi++) {
        int rowb = m0 + wm * 64 + mi * 16 + g * 4;
        #pragma unroll
        for (int ni = 0; ni < 4; ni++) {
            int col = n0 + wn * 64 + ni * 16 + c;
            #pragma unroll
            for (int r = 0; r < 4; r++)
                outF[(size_t)(rowb + r) * CDIM + col] = acc[mi][ni][r];
        }
    }
}

// ---------------------------------------------------------------------------
// attn: LDS-free main loop; permlane32_swap exchange; packed fixed-m softmax;
// setprio around MFMA. 4 s-chunks/block (one per wave);
// grid 2048 (64 ttiles x 32 hb, hb%8 = XCD).
__global__ __launch_bounds__(256, 4) void attn(const u16* __restrict__ qF, const u16* __restrict__ kF,
                                               const u16* __restrict__ vF,
                                               const float* __restrict__ ksC2T, u16* __restrict__ ao) {
    int bid = blockIdx.x;
    int hb = bid & 31;
    int ttile = bid >> 5;
    int tid = threadIdx.x, sc = tid >> 6, l = tid & 63;
    int hi = l >> 5, t32 = l & 31;

    __shared__ float redO[2][64][33];
    __shared__ float Ls[32];

    const u16* qbase = qF + ((size_t)hb * 64 + ttile) * 2048;
    short8 qf[4];
    #pragma unroll
    for (int ks = 0; ks < 4; ks++)
        qf[ks] = *reinterpret_cast<const short8*>(qbase + ks * 512 + (size_t)l * 8);

    const u16* kbase = kF + (size_t)hb * (64 * 2048);
    const u16* vbase = vF + (size_t)hb * (2 * 64 * 1024);
    const float* ksb = ksC2T + (size_t)hb * TSEQ;

    floatx16 oacc[2] = {};
    float lrun = 0.f;

    int st0 = sc * 16;
    #pragma unroll 2
    for (int st = st0; st < st0 + 16; ++st) {
        const short8* kp = reinterpret_cast<const short8*>(kbase + (size_t)st * 2048) + l;
        short8 kf0 = kp[0], kf1 = kp[64], kf2 = kp[128], kf3 = kp[192];
        const short8* vp = reinterpret_cast<const short8*>(vbase + (size_t)st * 1024) + l;
        short8 vf00 = vp[0], vf01 = vp[64];
        short8 vf10 = vp[8192], vf11 = vp[8256];

        __builtin_amdgcn_s_setprio(1);
        floatx16 sxx = {};
        sxx = __builtin_amdgcn_mfma_f32_32x32x16_bf16(kf0, qf[0], sxx, 0, 0, 0);
        sxx = __builtin_amdgcn_mfma_f32_32x32x16_bf16(kf1, qf[1], sxx, 0, 0, 0);
        sxx = __builtin_amdgcn_mfma_f32_32x32x16_bf16(kf2, qf[2], sxx, 0, 0, 0);
        sxx = __builtin_amdgcn_mfma_f32_32x32x16_bf16(kf3, qf[3], sxx, 0, 0, 0);
        __builtin_amdgcn_s_setprio(0);

        u32 pk[8];
        #pragma unroll
        for (int qq = 0; qq < 4; qq++) {
            float4 kc = *reinterpret_cast<const float4*>(&ksb[st * 32 + qq * 8 + hi * 4]);
            float p0 = exp2f(fmaf(sxx[qq * 4 + 0], M2C2_CONST, kc.x));
            float p1 = exp2f(fmaf(sxx[qq * 4 + 1], M2C2_CONST, kc.y));
            float p2 = exp2f(fmaf(sxx[qq * 4 + 2], M2C2_CONST, kc.z));
            float p3 = exp2f(fmaf(sxx[qq * 4 + 3], M2C2_CONST, kc.w));
            lrun += (p0 + p1) + (p2 + p3);
            pk[qq * 2]     = cvtpk(p0, p1);
            pk[qq * 2 + 1] = cvtpk(p2, p3);
        }

        __builtin_amdgcn_s_setprio(1);
        #pragma unroll
        for (int e = 0; e < 2; e++) {
            int2v r02 = __builtin_amdgcn_permlane32_swap((int)pk[4 * e + 2], (int)pk[4 * e + 0], false, false);
            int2v r13 = __builtin_amdgcn_permlane32_swap((int)pk[4 * e + 3], (int)pk[4 * e + 1], false, false);
            uint4v au;
            au.x = (u32)r02.y;
            au.y = (u32)r13.y;
            au.z = (u32)r02.x;
            au.w = (u32)r13.x;
            short8 af = __builtin_bit_cast(short8, au);
            oacc[0] = __builtin_amdgcn_mfma_f32_32x32x16_bf16(af, e ? vf01 : vf00, oacc[0], 0, 0, 0);
            oacc[1] = __builtin_amdgcn_mfma_f32_32x32x16_bf16(af, e ? vf11 : vf10, oacc[1], 0, 0, 0);
        }
        __builtin_amdgcn_s_setprio(0);
    }

    // ---- two-round combine of the 4 s-chunks (fixed-m: partials just add)
    if (sc == 1 || sc == 3) {
        int sid = sc >> 1;
        #pragma unroll
        for (int dt = 0; dt < 2; dt++)
            #pragma unroll
            for (int r = 0; r < 16; r++)
                redO[sid][l][dt * 16 + r] = oacc[dt][r];
        redO[sid][l][32] = lrun;
    }
    __syncthreads();
    if (sc == 0 || sc == 2) {
        int sid = sc >> 1;
        #pragma unroll
        for (int dt = 0; dt < 2; dt++)
            #pragma unroll
            for (int r = 0; r < 16; r++)
                oacc[dt][r] += redO[sid][l][dt * 16 + r];
        lrun += redO[sid][l][32];
    }
    __syncthreads();
    if (sc == 2) {
        #pragma unroll
        for (int dt = 0; dt < 2; dt++)
            #pragma unroll
            for (int r = 0; r < 16; r++)
                redO[0][l][dt * 16 + r] = oacc[dt][r];
        redO[0][l][32] = lrun;
    }
    __syncthreads();
    if (sc == 0) {
        #pragma unroll
        for (int dt = 0; dt < 2; dt++)
            #pragma unroll
            for (int r = 0; r < 16; r++)
                oacc[dt][r] += redO[0][l][dt * 16 + r];
        lrun += redO[0][l][32];

        float ltot = lrun + __shfl_xor(lrun, 32, 64);
        if (l < 32) Ls[l] = ltot;
        int b = hb >> 4, h = hb & 15;
        int twb = ttile * 32;
        float4 lv[4];
        #pragma unroll
        for (int qq = 0; qq < 4; qq++)
            lv[qq] = *reinterpret_cast<const float4*>(&Ls[qq * 8 + hi * 4]);
        #pragma unroll
        for (int dt = 0; dt < 2; dt++)
            #pragma unroll
            for (int r = 0; r < 16; ++r) {
                int trow = (r & 3) + 8 * (r >> 2) + 4 * hi;
                float lval = (r & 3) == 0 ? lv[r >> 2].x : (r & 3) == 1 ? lv[r >> 2].y
                           : (r & 3) == 2 ? lv[r >> 2].z : lv[r >> 2].w;
                ao[(size_t)(b * TSEQ + twb + trow) * CDIM + h * HDIM + dt * 32 + t32] =
                    f2bf(oacc[dt][r] * __builtin_amdgcn_rcpf(lval));
            }
    }
}

// ---------------------------------------------------------------------------
extern "C" void kernel_launch(void* const* d_in, const int* in_sizes, int n_in,
                              void* d_out, int out_size, void* d_ws, size_t ws_size,
                              hipStream_t stream) {
    const float* x  = (const float*)d_in[0];
    const float* Wq = (const float*)d_in[1];
    const float* gq = (const float*)d_in[2];
    const float* Wk = (const float*)d_in[3];
    const float* gk = (const float*)d_in[4];
    const float* Wv = (const float*)d_in[5];
    const float* gv = (const float*)d_in[6];
    const float* Wo = (const float*)d_in[7];
    float* out = (float*)d_out;

    char* p = (char*)d_ws;
    u16* xa  = (u16*)p;  p += (size_t)8 << 20;
    u16* qF  = (u16*)p;  p += (size_t)8 << 20;
    u16* kF  = (u16*)p;  p += (size_t)8 << 20;
    u16* vF  = (u16*)p;  p += (size_t)8 << 20;
    u16* ao  = (u16*)p;  p += (size_t)8 << 20;
    u16* waq = (u16*)p;  p += (size_t)2 << 20;
    u16* wak = (u16*)p;  p += (size_t)2 << 20;
    u16* wav = (u16*)p;  p += (size_t)2 << 20;
    u16* wob = (u16*)p;  p += (size_t)2 << 20;
    float* xsq   = (float*)p; p += 4096 * 4;
    float* sqq   = (float*)p; p += 1024 * 4;
    float* sqk   = (float*)p; p += 1024 * 4;
    float* sqv   = (float*)p; p += 1024 * 4;
    float* ksC2T = (float*)p; p += 4096 * 16 * 4;
    (void)ws_size; (void)in_sizes; (void)n_in; (void)out_size;

    prep<<<8192, 256, 0, stream>>>(x, Wq, Wk, Wv, Wo, xa, waq, wak, wav, wob,
                                   xsq, sqq, sqk, sqv);

    dim3 gqkv(8, 32, 3);
    gemm_qkv<<<gqkv, 256, 0, stream>>>(xa, waq, wak, wav, qF, kF, vF, xsq,
                                       sqq, sqk, sqv, gq, gk, gv);

    knorm<<<256, 256, 0, stream>>>(kF, ksC2T);

    attn<<<2048, 256, 0, stream>>>(qF, kF, vF, ksC2T, ao);

    dim3 gg(8, 32);
    gemm_out<<<gg, 256, 0, stream>>>(ao, wob, out);
}

// Round 13
// 140.079 us; speedup vs baseline: 1.0245x; 1.0225x over previous
//
#include <hip/hip_runtime.h>
#include <hip/hip_bf16.h>
#include <math.h>

typedef unsigned short u16;
typedef unsigned int u32;
typedef __attribute__((ext_vector_type(8))) short short8;
typedef __attribute__((ext_vector_type(8))) unsigned short ushort8;
typedef __attribute__((ext_vector_type(4))) float floatx4;
typedef __attribute__((ext_vector_type(16))) float floatx16;
typedef __attribute__((ext_vector_type(4))) u32 uint4v;
typedef __attribute__((ext_vector_type(2))) int int2v;

#define CDIM   1024
#define TSEQ   2048
#define NHEAD  16
#define HDIM   64

// -1/(80*ln2): exp(-dist/80) = exp2(dist * C2)
#define C2_CONST  (-0.01803368801111874f)
#define M2C2_CONST (0.03606737602223748f)

static __device__ __forceinline__ u16 f2bf(float f) {
    u32 u = __float_as_uint(f);
    u += 0x7fffu + ((u >> 16) & 1u);   // RNE
    return (u16)(u >> 16);
}

// packed f32x2 -> bf16x2 (RNE), single VOP3
static __device__ __forceinline__ u32 cvtpk(float a, float b) {
    u32 r;
    asm("v_cvt_pk_bf16_f32 %0, %1, %2" : "=v"(r) : "v"(a), "v"(b));
    return r;
}

// fast tanh: 1 - 2/(exp2(2x*log2e)+1)
static __device__ __forceinline__ float ftanh(float x) {
    float e = exp2f(x * 2.88539008f);
    float r = __builtin_amdgcn_rcpf(e + 1.0f);
    return fmaf(-2.0f, r, 1.0f);
}

// async global->LDS, 16 bytes per lane
static __device__ __forceinline__ void gll16(const void* g, void* l) {
    __builtin_amdgcn_global_load_lds(
        (const __attribute__((address_space(1))) unsigned int*)g,
        (__attribute__((address_space(3))) unsigned int*)l, 16, 0, 0);
}

// ---------------------------------------------------------------------------
// prep: bid<4096 -> xa=tanh(x)+xsq ; else W mats (tanh+wsq for q/k/v, copy Wo)
__global__ __launch_bounds__(256) void prep(const float* __restrict__ x,
                                            const float* __restrict__ Wq, const float* __restrict__ Wk,
                                            const float* __restrict__ Wv, const float* __restrict__ Wo,
                                            u16* __restrict__ xa,
                                            u16* __restrict__ waq, u16* __restrict__ wak,
                                            u16* __restrict__ wav, u16* __restrict__ wob,
                                            float* __restrict__ xsq,
                                            float* __restrict__ sqq, float* __restrict__ sqk,
                                            float* __restrict__ sqv) {
    __shared__ float red[4];
    int bid = blockIdx.x, tid = threadIdx.x;
    const float* src; u16* dst; float* sq; int row; bool do_tanh = true;
    if (bid < 4096) {
        row = bid; src = x; dst = xa; sq = xsq;
    } else {
        int mat = (bid - 4096) >> 10; row = (bid - 4096) & 1023;
        src = (mat == 0) ? Wq : (mat == 1) ? Wk : (mat == 2) ? Wv : Wo;
        dst = (mat == 0) ? waq : (mat == 1) ? wak : (mat == 2) ? wav : wob;
        sq  = (mat == 0) ? sqq : (mat == 1) ? sqk : (mat == 2) ? sqv : nullptr;
        do_tanh = (mat < 3);
    }
    float4 v = reinterpret_cast<const float4*>(src + (size_t)row * CDIM)[tid];
    if (do_tanh) {
        float a0 = ftanh(v.x), a1 = ftanh(v.y), a2 = ftanh(v.z), a3 = ftanh(v.w);
        *reinterpret_cast<ushort4*>(dst + (size_t)row * CDIM + tid * 4) =
            make_ushort4(f2bf(a0), f2bf(a1), f2bf(a2), f2bf(a3));
        float s = a0*a0 + a1*a1 + a2*a2 + a3*a3;
        #pragma unroll
        for (int m = 1; m < 64; m <<= 1) s += __shfl_xor(s, m, 64);
        if ((tid & 63) == 0) red[tid >> 6] = s;
        __syncthreads();
        if (tid == 0 && sq) sq[row] = red[0] + red[1] + red[2] + red[3];
    } else {
        *reinterpret_cast<ushort4*>(dst + (size_t)row * CDIM + tid * 4) =
            make_ushort4(f2bf(v.x), f2bf(v.y), f2bf(v.z), f2bf(v.w));
    }
}

// ---------------------------------------------------------------------------
// Fused QKV GEMM: C = A * Bm^T, distance epilogue; z = 0(q)/1(k)/2(v).
// Outputs in MFMA-FRAGMENT layout, written via LDS-bounce + linear copy-out.
// k epilogue also computes ksC2T[hb*2048+t] = C2 * sum_d k[t][d]^2 in-place
// (th values are live in registers there; saves a separate knorm dispatch).
__global__ __launch_bounds__(256) void gemm_qkv(const u16* __restrict__ xa,
                                                const u16* __restrict__ waq, const u16* __restrict__ wak, const u16* __restrict__ wav,
                                                u16* __restrict__ qF, u16* __restrict__ kF, u16* __restrict__ vF,
                                                const float* __restrict__ xsq,
                                                const float* __restrict__ sqq, const float* __restrict__ sqk, const float* __restrict__ sqv,
                                                const float* __restrict__ gq, const float* __restrict__ gk, const float* __restrict__ gv,
                                                float* __restrict__ ksC2T) {
    __shared__ __align__(16) u16 SMEM[2 * 128 * 64];   // As|Bs in loop; 32KB frag-staging in epilogue
    u16* As = SMEM;
    u16* Bs = SMEM + 128 * 64;
    int z = blockIdx.z;
    const u16* Bm     = (z == 0) ? waq : (z == 1) ? wak : wav;
    const float* wsq  = (z == 0) ? sqq : (z == 1) ? sqk : sqv;
    const float* gain = (z == 0) ? gq : (z == 1) ? gk : gv;

    int tid = threadIdx.x;
    int m0 = blockIdx.y * 128, n0 = blockIdx.x * 128;
    int w = tid >> 6, l = tid & 63, wm = w >> 1, wn = w & 1, g = l >> 4, c = l & 15;
    int r8 = l >> 3, sl7 = l & 7;
    int cmask = (c & 7) ^ (c >> 3);

    floatx4 acc[4][4] = {};

    for (int kt = 0; kt < 16; ++kt) {
        __syncthreads();
        #pragma unroll
        for (int i = 0; i < 4; i++) {
            int ch = w * 4 + i;
            int row = ch * 8 + r8;
            int sl = sl7 ^ r8 ^ (ch & 1);
            gll16(xa + (size_t)(m0 + row) * CDIM + kt * 64 + sl * 8, &As[ch * 512 + l * 8]);
            gll16(Bm + (size_t)(n0 + row) * CDIM + kt * 64 + sl * 8, &Bs[ch * 512 + l * 8]);
        }
        __syncthreads();
        short8 af[2][4], bf[2][4];
        #pragma unroll
        for (int kk = 0; kk < 2; kk++) {
            #pragma unroll
            for (int mi = 0; mi < 4; mi++)
                af[kk][mi] = *reinterpret_cast<const short8*>(
                    &As[(wm * 64 + mi * 16 + c) * 64 + (((kk * 4 + g) ^ cmask) << 3)]);
            #pragma unroll
            for (int ni = 0; ni < 4; ni++)
                bf[kk][ni] = *reinterpret_cast<const short8*>(
                    &Bs[(wn * 64 + ni * 16 + c) * 64 + (((kk * 4 + g) ^ cmask) << 3)]);
        }
        #pragma unroll
        for (int kk = 0; kk < 2; kk++)
            #pragma unroll
            for (int mi = 0; mi < 4; mi++)
                #pragma unroll
                for (int ni = 0; ni < 4; ni++)
                    acc[mi][ni] = __builtin_amdgcn_mfma_f32_16x16x32_bf16(af[kk][mi], bf[kk][ni], acc[mi][ni], 0, 0, 0);
    }

    __syncthreads();   // all MFMA LDS reads complete before SMEM reuse

    int bb = m0 >> 11;                 // batch
    int tile0 = (m0 & 2047) >> 5;      // first 32-row tile (multiple of 4)
    int hh0 = blockIdx.x * 2;          // first head of this block's 128 cols

    if (z < 2) {
        u16* outF = (z == 0) ? qF : kF;
        float part[4][4] = {};
        // ---- scatter into SMEM in attn-frag layout:
        // lidx = hh2*8192 + tile4*2048 + kst*512 + hi8*256 + l31*8 + j
        #pragma unroll
        for (int mi = 0; mi < 4; mi++) {
            int rowb = m0 + wm * 64 + mi * 16 + g * 4;
            int tile4 = (rowb & 127) >> 5;
            int l31 = rowb & 31;       // rowb%32; +r below (r<4, l31%4==0)
            #pragma unroll
            for (int ni = 0; ni < 4; ni++) {
                int col = n0 + wn * 64 + ni * 16 + c;
                int hh2 = (col >> 6) & 1;  // == wn for all ni
                int d = col & 63;
                int kst = d >> 4, hi8 = (d >> 3) & 1, j = d & 7;
                int lidx = hh2 * 8192 + tile4 * 2048 + kst * 512 + hi8 * 256 + l31 * 8 + j;
                float wsqc = wsq[col], gn = gain[col];
                #pragma unroll
                for (int r = 0; r < 4; r++) {
                    float l2 = fmaxf(xsq[rowb + r] + wsqc - 2.f * acc[mi][ni][r], 0.f);
                    float th = ftanh((0.5f - l2 * (1.f / 1024.f)) * gn);
                    SMEM[lidx + r * 8] = f2bf(th);
                    part[mi][r] += th * th;
                }
            }
        }
        if (z == 1) {   // fused k-norm: per-head row sq * C2 (head = hh0 + wn)
            #pragma unroll
            for (int mi = 0; mi < 4; mi++)
                #pragma unroll
                for (int r = 0; r < 4; r++) {
                    float s = part[mi][r];
                    s += __shfl_xor(s, 1, 64); s += __shfl_xor(s, 2, 64);
                    s += __shfl_xor(s, 4, 64); s += __shfl_xor(s, 8, 64);
                    if (c == 0) {
                        int row = m0 + wm * 64 + mi * 16 + g * 4 + r;
                        int t = row & 2047;
                        ksC2T[(size_t)(bb * NHEAD + hh0 + wn) * TSEQ + t] = s * C2_CONST;
                    }
                }
        }
        __syncthreads();
        // ---- linear copy-out: 2 contiguous spans of 8192 u16 (one per head)
        #pragma unroll
        for (int hh2 = 0; hh2 < 2; hh2++) {
            u16* gdst = outF + (((size_t)(bb * NHEAD + hh0 + hh2) * 64 + tile0) * 2048);
            #pragma unroll
            for (int i = 0; i < 4; i++) {
                int off = i * 2048 + tid * 8;
                *reinterpret_cast<ushort8*>(gdst + off) =
                    *reinterpret_cast<const ushort8*>(&SMEM[hh2 * 8192 + off]);
            }
        }
    } else {
        // ---- v: scatter into SMEM in PV B-frag layout:
        // lidx = hh2*8192 + dt*4096 + tile4*1024 + e*512 + hi8*256 + l31*8 + j0
        #pragma unroll
        for (int mi = 0; mi < 4; mi++) {
            int rowb = m0 + wm * 64 + mi * 16 + g * 4;   // s
            int tile4 = (rowb & 127) >> 5;
            int e = (rowb >> 4) & 1, hi8 = (rowb >> 3) & 1, j0 = rowb & 7;
            #pragma unroll
            for (int ni = 0; ni < 4; ni++) {
                int col = n0 + wn * 64 + ni * 16 + c;
                int hh2 = (col >> 6) & 1;
                int d = col & 63;
                int dt = d >> 5, l31 = d & 31;
                float wsqc = wsq[col], gn = gain[col];
                float vals[4];
                #pragma unroll
                for (int r = 0; r < 4; r++) {
                    float l2 = fmaxf(xsq[rowb + r] + wsqc - 2.f * acc[mi][ni][r], 0.f);
                    vals[r] = (0.5f - l2 * (1.f / 1024.f)) * gn;
                }
                int lidx = hh2 * 8192 + dt * 4096 + tile4 * 1024 + e * 512 + hi8 * 256 + l31 * 8 + j0;
                *reinterpret_cast<ushort4*>(&SMEM[lidx]) =
                    make_ushort4(f2bf(vals[0]), f2bf(vals[1]), f2bf(vals[2]), f2bf(vals[3]));
            }
        }
        __syncthreads();
        // ---- linear copy-out: 4 contiguous spans of 4096 u16 per (head, dt)
        #pragma unroll
        for (int hh2 = 0; hh2 < 2; hh2++)
            #pragma unroll
            for (int dt = 0; dt < 2; dt++) {
                u16* gdst = vF + ((((size_t)(bb * NHEAD + hh0 + hh2) * 2 + dt) * 64 + tile0) * 1024);
                #pragma unroll
                for (int i = 0; i < 2; i++) {
                    int off = i * 2048 + tid * 8;
                    *reinterpret_cast<ushort8*>(gdst + off) =
                        *reinterpret_cast<const ushort8*>(&SMEM[hh2 * 8192 + dt * 4096 + off]);
                }
            }
    }
}

// ---------------------------------------------------------------------------
// Final GEMM: out = ao * Wo^T, f32 store.
__global__ __launch_bounds__(256) void gemm_out(const u16* __restrict__ A, const u16* __restrict__ Bm,
                                                float* __restrict__ outF) {
    __shared__ __align__(16) u16 As[128 * 64];
    __shared__ __align__(16) u16 Bs[128 * 64];
    int tid = threadIdx.x;
    int m0 = blockIdx.y * 128, n0 = blockIdx.x * 128;
    int w = tid >> 6, l = tid & 63, wm = w >> 1, wn = w & 1, g = l >> 4, c = l & 15;
    int r8 = l >> 3, sl7 = l & 7;
    int cmask = (c & 7) ^ (c >> 3);

    floatx4 acc[4][4] = {};

    for (int kt = 0; kt < 16; ++kt) {
        __syncthreads();
        #pragma unroll
        for (int i = 0; i < 4; i++) {
            int ch = w * 4 + i;
            int row = ch * 8 + r8;
            int sl = sl7 ^ r8 ^ (ch & 1);
            gll16(A + (size_t)(m0 + row) * CDIM + kt * 64 + sl * 8, &As[ch * 512 + l * 8]);
            gll16(Bm + (size_t)(n0 + row) * CDIM + kt * 64 + sl * 8, &Bs[ch * 512 + l * 8]);
        }
        __syncthreads();
        short8 af[2][4], bf[2][4];
        #pragma unroll
        for (int kk = 0; kk < 2; kk++) {
            #pragma unroll
            for (int mi = 0; mi < 4; mi++)
                af[kk][mi] = *reinterpret_cast<const short8*>(
                    &As[(wm * 64 + mi * 16 + c) * 64 + (((kk * 4 + g) ^ cmask) << 3)]);
            #pragma unroll
            for (int ni = 0; ni < 4; ni++)
                bf[kk][ni] = *reinterpret_cast<const short8*>(
                    &Bs[(wn * 64 + ni * 16 + c) * 64 + (((kk * 4 + g) ^ cmask) << 3)]);
        }
        #pragma unroll
        for (int kk = 0; kk < 2; kk++)
            #pragma unroll
            for (int mi = 0; mi < 4; mi++)
                #pragma unroll
                for (int ni = 0; ni < 4; ni++)
                    acc[mi][ni] = __builtin_amdgcn_mfma_f32_16x16x32_bf16(af[kk][mi], bf[kk][ni], acc[mi][ni], 0, 0, 0);
    }

    #pragma unroll
    for (int mi = 0; mi < 4; mi++) {
        int rowb = m0 + wm * 64 + mi * 16 + g * 4;
        #pragma unroll
        for (int ni = 0; ni < 4; ni++) {
            int col = n0 + wn * 64 + ni * 16 + c;
            #pragma unroll
            for (int r = 0; r < 4; r++)
                outF[(size_t)(rowb + r) * CDIM + col] = acc[mi][ni][r];
        }
    }
}

// ---------------------------------------------------------------------------
// attn: LDS-free main loop; permlane32_swap exchange; packed fixed-m softmax;
// setprio around MFMA. 4 s-chunks/block (one per wave);
// grid 2048 (64 ttiles x 32 hb, hb%8 = XCD).
__global__ __launch_bounds__(256, 4) void attn(const u16* __restrict__ qF, const u16* __restrict__ kF,
                                               const u16* __restrict__ vF,
                                               const float* __restrict__ ksC2T, u16* __restrict__ ao) {
    int bid = blockIdx.x;
    int hb = bid & 31;
    int ttile = bid >> 5;
    int tid = threadIdx.x, sc = tid >> 6, l = tid & 63;
    int hi = l >> 5, t32 = l & 31;

    __shared__ float redO[2][64][33];
    __shared__ float Ls[32];

    const u16* qbase = qF + ((size_t)hb * 64 + ttile) * 2048;
    short8 qf[4];
    #pragma unroll
    for (int ks = 0; ks < 4; ks++)
        qf[ks] = *reinterpret_cast<const short8*>(qbase + ks * 512 + (size_t)l * 8);

    const u16* kbase = kF + (size_t)hb * (64 * 2048);
    const u16* vbase = vF + (size_t)hb * (2 * 64 * 1024);
    const float* ksb = ksC2T + (size_t)hb * TSEQ;

    floatx16 oacc[2] = {};
    float lrun = 0.f;

    int st0 = sc * 16;
    #pragma unroll 2
    for (int st = st0; st < st0 + 16; ++st) {
        const short8* kp = reinterpret_cast<const short8*>(kbase + (size_t)st * 2048) + l;
        short8 kf0 = kp[0], kf1 = kp[64], kf2 = kp[128], kf3 = kp[192];
        const short8* vp = reinterpret_cast<const short8*>(vbase + (size_t)st * 1024) + l;
        short8 vf00 = vp[0], vf01 = vp[64];
        short8 vf10 = vp[8192], vf11 = vp[8256];

        __builtin_amdgcn_s_setprio(1);
        floatx16 sxx = {};
        sxx = __builtin_amdgcn_mfma_f32_32x32x16_bf16(kf0, qf[0], sxx, 0, 0, 0);
        sxx = __builtin_amdgcn_mfma_f32_32x32x16_bf16(kf1, qf[1], sxx, 0, 0, 0);
        sxx = __builtin_amdgcn_mfma_f32_32x32x16_bf16(kf2, qf[2], sxx, 0, 0, 0);
        sxx = __builtin_amdgcn_mfma_f32_32x32x16_bf16(kf3, qf[3], sxx, 0, 0, 0);
        __builtin_amdgcn_s_setprio(0);

        u32 pk[8];
        #pragma unroll
        for (int qq = 0; qq < 4; qq++) {
            float4 kc = *reinterpret_cast<const float4*>(&ksb[st * 32 + qq * 8 + hi * 4]);
            float p0 = exp2f(fmaf(sxx[qq * 4 + 0], M2C2_CONST, kc.x));
            float p1 = exp2f(fmaf(sxx[qq * 4 + 1], M2C2_CONST, kc.y));
            float p2 = exp2f(fmaf(sxx[qq * 4 + 2], M2C2_CONST, kc.z));
            float p3 = exp2f(fmaf(sxx[qq * 4 + 3], M2C2_CONST, kc.w));
            lrun += (p0 + p1) + (p2 + p3);
            pk[qq * 2]     = cvtpk(p0, p1);
            pk[qq * 2 + 1] = cvtpk(p2, p3);
        }

        __builtin_amdgcn_s_setprio(1);
        #pragma unroll
        for (int e = 0; e < 2; e++) {
            int2v r02 = __builtin_amdgcn_permlane32_swap((int)pk[4 * e + 2], (int)pk[4 * e + 0], false, false);
            int2v r13 = __builtin_amdgcn_permlane32_swap((int)pk[4 * e + 3], (int)pk[4 * e + 1], false, false);
            uint4v au;
            au.x = (u32)r02.y;
            au.y = (u32)r13.y;
            au.z = (u32)r02.x;
            au.w = (u32)r13.x;
            short8 af = __builtin_bit_cast(short8, au);
            oacc[0] = __builtin_amdgcn_mfma_f32_32x32x16_bf16(af, e ? vf01 : vf00, oacc[0], 0, 0, 0);
            oacc[1] = __builtin_amdgcn_mfma_f32_32x32x16_bf16(af, e ? vf11 : vf10, oacc[1], 0, 0, 0);
        }
        __builtin_amdgcn_s_setprio(0);
    }

    // ---- two-round combine of the 4 s-chunks (fixed-m: partials just add)
    if (sc == 1 || sc == 3) {
        int sid = sc >> 1;
        #pragma unroll
        for (int dt = 0; dt < 2; dt++)
            #pragma unroll
            for (int r = 0; r < 16; r++)
                redO[sid][l][dt * 16 + r] = oacc[dt][r];
        redO[sid][l][32] = lrun;
    }
    __syncthreads();
    if (sc == 0 || sc == 2) {
        int sid = sc >> 1;
        #pragma unroll
        for (int dt = 0; dt < 2; dt++)
            #pragma unroll
            for (int r = 0; r < 16; r++)
                oacc[dt][r] += redO[sid][l][dt * 16 + r];
        lrun += redO[sid][l][32];
    }
    __syncthreads();
    if (sc == 2) {
        #pragma unroll
        for (int dt = 0; dt < 2; dt++)
            #pragma unroll
            for (int r = 0; r < 16; r++)
                redO[0][l][dt * 16 + r] = oacc[dt][r];
        redO[0][l][32] = lrun;
    }
    __syncthreads();
    if (sc == 0) {
        #pragma unroll
        for (int dt = 0; dt < 2; dt++)
            #pragma unroll
            for (int r = 0; r < 16; r++)
                oacc[dt][r] += redO[0][l][dt * 16 + r];
        lrun += redO[0][l][32];

        float ltot = lrun + __shfl_xor(lrun, 32, 64);
        if (l < 32) Ls[l] = ltot;
        int b = hb >> 4, h = hb & 15;
        int twb = ttile * 32;
        float4 lv[4];
        #pragma unroll
        for (int qq = 0; qq < 4; qq++)
            lv[qq] = *reinterpret_cast<const float4*>(&Ls[qq * 8 + hi * 4]);
        #pragma unroll
        for (int dt = 0; dt < 2; dt++)
            #pragma unroll
            for (int r = 0; r < 16; ++r) {
                int trow = (r & 3) + 8 * (r >> 2) + 4 * hi;
                float lval = (r & 3) == 0 ? lv[r >> 2].x : (r & 3) == 1 ? lv[r >> 2].y
                           : (r & 3) == 2 ? lv[r >> 2].z : lv[r >> 2].w;
                ao[(size_t)(b * TSEQ + twb + trow) * CDIM + h * HDIM + dt * 32 + t32] =
                    f2bf(oacc[dt][r] * __builtin_amdgcn_rcpf(lval));
            }
    }
}

// ---------------------------------------------------------------------------
extern "C" void kernel_launch(void* const* d_in, const int* in_sizes, int n_in,
                              void* d_out, int out_size, void* d_ws, size_t ws_size,
                              hipStream_t stream) {
    const float* x  = (const float*)d_in[0];
    const float* Wq = (const float*)d_in[1];
    const float* gq = (const float*)d_in[2];
    const float* Wk = (const float*)d_in[3];
    const float* gk = (const float*)d_in[4];
    const float* Wv = (const float*)d_in[5];
    const float* gv = (const float*)d_in[6];
    const float* Wo = (const float*)d_in[7];
    float* out = (float*)d_out;

    char* p = (char*)d_ws;
    u16* xa  = (u16*)p;  p += (size_t)8 << 20;
    u16* qF  = (u16*)p;  p += (size_t)8 << 20;
    u16* kF  = (u16*)p;  p += (size_t)8 << 20;
    u16* vF  = (u16*)p;  p += (size_t)8 << 20;
    u16* ao  = (u16*)p;  p += (size_t)8 << 20;
    u16* waq = (u16*)p;  p += (size_t)2 << 20;
    u16* wak = (u16*)p;  p += (size_t)2 << 20;
    u16* wav = (u16*)p;  p += (size_t)2 << 20;
    u16* wob = (u16*)p;  p += (size_t)2 << 20;
    float* xsq   = (float*)p; p += 4096 * 4;
    float* sqq   = (float*)p; p += 1024 * 4;
    float* sqk   = (float*)p; p += 1024 * 4;
    float* sqv   = (float*)p; p += 1024 * 4;
    float* ksC2T = (float*)p; p += 4096 * 16 * 4;
    (void)ws_size; (void)in_sizes; (void)n_in; (void)out_size;

    prep<<<8192, 256, 0, stream>>>(x, Wq, Wk, Wv, Wo, xa, waq, wak, wav, wob,
                                   xsq, sqq, sqk, sqv);

    dim3 gqkv(8, 32, 3);
    gemm_qkv<<<gqkv, 256, 0, stream>>>(xa, waq, wak, wav, qF, kF, vF, xsq,
                                       sqq, sqk, sqv, gq, gk, gv, ksC2T);

    attn<<<2048, 256, 0, stream>>>(qF, kF, vF, ksC2T, ao);

    dim3 gg(8, 32);
    gemm_out<<<gg, 256, 0, stream>>>(ao, wob, out);
}